// Round 11
// baseline (870.138 us; speedup 1.0000x reference)
//
#include <hip/hip_runtime.h>
#include <hip/hip_bf16.h>
#include <math.h>

#define H 128

typedef __bf16 bf16x8 __attribute__((ext_vector_type(8)));
typedef float f32x4 __attribute__((ext_vector_type(4)));
typedef float f32x2 __attribute__((ext_vector_type(2)));
typedef __hip_bfloat16 bf16;
typedef unsigned int uint32;

static __device__ __forceinline__ float bf2f(bf16 v){ return __bfloat162float(v); }
static __device__ __forceinline__ bf16 f2bf(float v){ return __float2bfloat16(v); }
static __device__ __forceinline__ float u2f_lo(uint32 v){ return __uint_as_float(v << 16); }
static __device__ __forceinline__ float u2f_hi(uint32 v){ return __uint_as_float(v & 0xffff0000u); }

union bfpack { struct { bf16 lo, hi; } h; uint32 u; };
static __device__ __forceinline__ uint32 pack_bf2(float a, float b){
  bfpack p; p.h.lo = f2bf(a); p.h.hi = f2bf(b); return p.u;
}

// ---------------------------------------------------------------------------
// Table layouts: PT[node][1024], LT[node][512], weights permuted within
// 64-col groups. RBF nearest-bin table 256 bins (1.6 MB, L2-permanent).
// CSR edge info packed as int2 {src, float_bits(d)}.
// node_update: 2 waves per node (split edge lists, LDS combine).
// ---------------------------------------------------------------------------
static __device__ __forceinline__ int unperm64(int r){
  int base = r & ~63; int g = r & 63; int t = g >> 4; int j = g & 15;
  return base + 4*j + t;
}

#define NBIN 256
#define PREP_WP_N (4*1024*128)
#define PREP_WL_N (4*512*128)
#define RBF_N     (12*(NBIN+1)*128)

__global__ void prep_all(const float* __restrict__ Wf, const float* __restrict__ Ws,
                         const float* __restrict__ bfv, const float* __restrict__ bsv,
                         bf16* __restrict__ Wt_p, float* __restrict__ Bias_p,
                         bf16* __restrict__ Wt_l, float* __restrict__ Bias_l,
                         bf16* __restrict__ T2,
                         const float* __restrict__ Xp, const float* __restrict__ Wp,
                         const float* __restrict__ bp, float* __restrict__ Xpo,
                         bf16* __restrict__ Xpb, int NP,
                         const float* __restrict__ Xl, const float* __restrict__ Wl,
                         const float* __restrict__ bl, float* __restrict__ Xlo,
                         bf16* __restrict__ Xlb, int NL){
  int t = blockIdx.x*blockDim.x + threadIdx.x;
  if (t < PREP_WP_N){
    int k = t & 127; int idx = t >> 7;
    int rs = idx & 1023; int l = idx >> 10;
    int r = unperm64(rs);
    int rel, c, row0; const float* W; float bias = 0.f;
    if (r < 256)      { rel=0; c=r>>1;        row0=128; W = (r&1)?Ws:Wf; }
    else if (r < 512) { rel=2; c=(r-256)>>1;  row0=128; W = (r&1)?Ws:Wf; }
    else if (r < 640) { rel=0; c=r-512; row0=0; W=Wf; bias = bfv[(l*3+rel)*H+c]; }
    else if (r < 768) { rel=0; c=r-640; row0=0; W=Ws; bias = bsv[(l*3+rel)*H+c]; }
    else if (r < 896) { rel=1; c=r-768; row0=0; W=Wf; bias = bfv[(l*3+rel)*H+c]; }
    else              { rel=1; c=r-896; row0=0; W=Ws; bias = bsv[(l*3+rel)*H+c]; }
    Wt_p[t] = f2bf(W[((size_t)(l*3+rel)*272 + row0 + k)*H + c]);
    if (k == 0) Bias_p[l*1024 + r] = bias;
    return;
  }
  t -= PREP_WP_N;
  if (t < PREP_WL_N){
    int k = t & 127; int idx = t >> 7;
    int rs = idx & 511; int l = idx >> 9;
    int r = unperm64(rs);
    int rel, c, row0; const float* W; float bias = 0.f;
    if (r < 256)      { rel=1; c=r>>1;   row0=128; W = (r&1)?Ws:Wf; }
    else if (r < 384) { rel=2; c=r-256; row0=0; W=Wf; bias = bfv[(l*3+rel)*H+c]; }
    else              { rel=2; c=r-384; row0=0; W=Ws; bias = bsv[(l*3+rel)*H+c]; }
    Wt_l[t] = f2bf(W[((size_t)(l*3+rel)*272 + row0 + k)*H + c]);
    if (k == 0) Bias_l[l*512 + r] = bias;
    return;
  }
  t -= PREP_WL_N;
  if (t < RBF_N){
    int c = t & 127;
    int b = (t >> 7) % (NBIN+1);
    int pr = t / ((NBIN+1)*128);
    float d0 = (float)b * (8.0f/(float)NBIN);
    const float* wf = Wf + ((size_t)pr*272 + 256)*H + c;
    const float* ws = Ws + ((size_t)pr*272 + 256)*H + c;
    float f0=0.f, s0=0.f;
    #pragma unroll
    for (int k=0;k<16;k++){
      float o = 0.533333333f*(float)k;
      float tt = d0 - o;
      float r0 = __expf(-1.7578125f*tt*tt);
      f0 += r0*wf[(size_t)k*H]; s0 += r0*ws[(size_t)k*H];
    }
    bf16* o = T2 + ((size_t)(pr*(NBIN+1) + b))*256 + 2*c;
    o[0]=f2bf(f0); o[1]=f2bf(s0);
    return;
  }
  t -= RBF_N;
  { // embeddings
    int idx = t;
    const float* Xin; const float* W; const float* b; float* Xout; bf16* Xbf;
    if (idx < NP*H){ Xin=Xp; W=Wp; b=bp; Xout=Xpo; Xbf=Xpb; }
    else { idx -= NP*H; if (idx >= NL*H) return; Xin=Xl; W=Wl; b=bl; Xout=Xlo; Xbf=Xlb; }
    int n = idx >> 7, c = idx & 127;
    float acc = b[c];
    #pragma unroll
    for (int k=0;k<6;k++) acc += Xin[n*6+k] * W[k*H+c];
    Xout[idx] = acc;
    Xbf[idx] = f2bf(acc);
  }
}

// ---------------------------------------------------------------------------
// CSR build: hist -> chunk sums -> mid scan -> final scan -> fill
// ---------------------------------------------------------------------------
__global__ void hist3_k(const int* __restrict__ dpp, int Epp,
                        const int* __restrict__ dlp, int Elp,
                        const int* __restrict__ dpl, int Epl,
                        int* __restrict__ cpp, int* __restrict__ clp, int* __restrict__ cpl){
  int e = blockIdx.x*blockDim.x + threadIdx.x;
  if (e < Epp) atomicAdd(&cpp[dpp[e]], 1);
  else if (e < Epp+Elp) atomicAdd(&clp[dlp[e-Epp]], 1);
  else if (e < Epp+Elp+Epl) atomicAdd(&cpl[dpl[e-Epp-Elp]], 1);
}

#define SCH 1024   // scan chunk size

__global__ void __launch_bounds__(256) chunksum_k(
    const int* __restrict__ counts, int NP, int NL, int Cpp, int Cpl,
    int* __restrict__ chsum){
  __shared__ int wred[4];
  int b = blockIdx.x;
  const int* cnt; int n; int ch;
  if (b < Cpp){ cnt = counts; n = NP; ch = b; }
  else if (b < 2*Cpp){ cnt = counts + NP; n = NP; ch = b - Cpp; }
  else { cnt = counts + 2*NP; n = NL; ch = b - 2*Cpp; }
  int base = ch * SCH;
  int tid = threadIdx.x;
  int s = 0;
  #pragma unroll
  for (int j=0;j<SCH/256;j++){
    int i = base + tid + j*256;
    if (i < n) s += cnt[i];
  }
  #pragma unroll
  for (int o=32;o>=1;o>>=1) s += __shfl_xor(s,o,64);
  if ((tid & 63) == 0) wred[tid>>6] = s;
  __syncthreads();
  if (tid == 0) chsum[b] = wred[0]+wred[1]+wred[2]+wred[3];
}

__global__ void __launch_bounds__(192) scanmid_k(
    int* __restrict__ chsum, int Cpp, int Cpl, int NP, int NL,
    int* __restrict__ rp_pp, int* __restrict__ rp_lp, int* __restrict__ rp_pl){
  int wid = threadIdx.x >> 6, lane = threadIdx.x & 63;
  int C, off; int* rp_end; int n;
  if (wid == 0){ C = Cpp; off = 0;      rp_end = rp_pp; n = NP; }
  else if (wid == 1){ C = Cpp; off = Cpp; rp_end = rp_lp; n = NP; }
  else { C = Cpl; off = 2*Cpp; rp_end = rp_pl; n = NL; }
  int v = (lane < C) ? chsum[off + lane] : 0;
  int x = v;
  #pragma unroll
  for (int o=1;o<64;o<<=1){
    int y = __shfl_up(x, o, 64);
    if (lane >= o) x += y;
  }
  if (lane < C) chsum[off + lane] = x - v;
  if (lane == 63) rp_end[n] = x;
}

__global__ void __launch_bounds__(1024) scanfin_k(
    const int* __restrict__ counts, int NP, int NL, int Cpp, int Cpl,
    const int* __restrict__ chsum,
    int* __restrict__ rp_pp, int* __restrict__ cur_pp,
    int* __restrict__ rp_lp, int* __restrict__ cur_lp,
    int* __restrict__ rp_pl, int* __restrict__ cur_pl){
  __shared__ int wsum[16];
  int b = blockIdx.x;
  const int* cnt; int n, ch; int* rp; int* cur;
  if (b < Cpp){ cnt = counts; n = NP; ch = b; rp = rp_pp; cur = cur_pp; }
  else if (b < 2*Cpp){ cnt = counts + NP; n = NP; ch = b - Cpp; rp = rp_lp; cur = cur_lp; }
  else { cnt = counts + 2*NP; n = NL; ch = b - 2*Cpp; rp = rp_pl; cur = cur_pl; }
  int tid = threadIdx.x, lane = tid & 63, wid = tid >> 6;
  int i = ch*SCH + tid;
  int v = (i < n) ? cnt[i] : 0;
  int x = v;
  #pragma unroll
  for (int o=1;o<64;o<<=1){
    int y = __shfl_up(x, o, 64);
    if (lane >= o) x += y;
  }
  if (lane == 63) wsum[wid] = x;
  __syncthreads();
  if (wid == 0 && lane < 16){
    int w = wsum[lane];
    #pragma unroll
    for (int o=1;o<16;o<<=1){
      int y = __shfl_up(w, o, 64);
      if (lane >= o) w += y;
    }
    wsum[lane] = w;
  }
  __syncthreads();
  int waveoff = (wid == 0) ? 0 : wsum[wid-1];
  int ex = chsum[b] + waveoff + x - v;
  if (i < n){ rp[i] = ex; cur[i] = ex; }
}

// fill packed int2 {src, d_bits}
__global__ void fill3_k(const int* __restrict__ ei_pp, const float* __restrict__ ea_pp, int Epp,
                        const int* __restrict__ ei_lp, const float* __restrict__ ea_lp, int Elp,
                        const int* __restrict__ ei_pl, const float* __restrict__ ea_pl, int Epl,
                        int* __restrict__ cur_pp, int2* __restrict__ e2_pp,
                        int* __restrict__ cur_lp, int2* __restrict__ e2_lp,
                        int* __restrict__ cur_pl, int2* __restrict__ e2_pl){
  int e = blockIdx.x*blockDim.x + threadIdx.x;
  if (e < Epp){
    int p = atomicAdd(&cur_pp[ei_pp[Epp + e]], 1);
    e2_pp[p] = make_int2(ei_pp[e], __float_as_int(ea_pp[e]));
  } else if (e < Epp+Elp){
    int i = e - Epp;
    int p = atomicAdd(&cur_lp[ei_lp[Elp + i]], 1);
    e2_lp[p] = make_int2(ei_lp[i], __float_as_int(ea_lp[i]));
  } else if (e < Epp+Elp+Epl){
    int i = e - Epp - Elp;
    int p = atomicAdd(&cur_pl[ei_pl[Epl + i]], 1);
    e2_pl[p] = make_int2(ei_pl[i], __float_as_int(ea_pl[i]));
  }
}

// ---------------------------------------------------------------------------
// Table GEMM v4 (B-resident): wave owns one 64-col group, iterates row strips.
// ---------------------------------------------------------------------------
#define GR 8
__global__ void __launch_bounds__(256) gemm_tables(
    const bf16* __restrict__ Xp, const bf16* __restrict__ Wtp,
    const float* __restrict__ Biasp, bf16* __restrict__ Outp,
    int strips_p, int tasks_p,
    const bf16* __restrict__ Xl, const bf16* __restrict__ Wtl,
    const float* __restrict__ Biasl, bf16* __restrict__ Outl,
    int strips_l, int tasks_total){
  int wt = blockIdx.x*4 + (threadIdx.x >> 6);
  if (wt >= tasks_total) return;
  const bf16 *X, *Wt; const float* Bias; bf16* Out; int N, strips, g, chunk;
  if (wt < tasks_p){
    X=Xp; Wt=Wtp; Bias=Biasp; Out=Outp; N=1024; strips=strips_p;
    g = wt & 15; chunk = wt >> 4;
  } else {
    int w = wt - tasks_p;
    X=Xl; Wt=Wtl; Bias=Biasl; Out=Outl; N=512; strips=strips_l;
    g = w & 7; chunk = w >> 3;
  }
  int n0 = g << 6;
  int lane = threadIdx.x & 63;
  int lr = lane & 15, lq = lane >> 4;
  const bf16x8* B0 = (const bf16x8*)(const void*)(Wt + (size_t)(n0      + lr)*H);
  const bf16x8* B1 = (const bf16x8*)(const void*)(Wt + (size_t)(n0 + 16 + lr)*H);
  const bf16x8* B2 = (const bf16x8*)(const void*)(Wt + (size_t)(n0 + 32 + lr)*H);
  const bf16x8* B3 = (const bf16x8*)(const void*)(Wt + (size_t)(n0 + 48 + lr)*H);
  bf16x8 b0_0=B0[lq], b0_1=B0[4+lq], b0_2=B0[8+lq], b0_3=B0[12+lq];
  bf16x8 b1_0=B1[lq], b1_1=B1[4+lq], b1_2=B1[8+lq], b1_3=B1[12+lq];
  bf16x8 b2_0=B2[lq], b2_1=B2[4+lq], b2_2=B2[8+lq], b2_3=B2[12+lq];
  bf16x8 b3_0=B3[lq], b3_1=B3[4+lq], b3_2=B3[8+lq], b3_3=B3[12+lq];
  float4 bias = ((const float4*)(const void*)(Bias + n0))[lr];
  #pragma unroll 2
  for (int r=0;r<GR;r++){
    int strip = chunk*GR + r;
    if (strip >= strips) break;
    int m0 = strip << 4;
    const bf16x8* A = (const bf16x8*)(const void*)(X + (size_t)(m0+lr)*H);
    bf16x8 a0 = A[lq], a1 = A[4+lq], a2 = A[8+lq], a3 = A[12+lq];
    f32x4 acc0 = {0.f,0.f,0.f,0.f}, acc1 = acc0, acc2 = acc0, acc3 = acc0;
    acc0 = __builtin_amdgcn_mfma_f32_16x16x32_bf16(a0, b0_0, acc0, 0, 0, 0);
    acc1 = __builtin_amdgcn_mfma_f32_16x16x32_bf16(a0, b1_0, acc1, 0, 0, 0);
    acc2 = __builtin_amdgcn_mfma_f32_16x16x32_bf16(a0, b2_0, acc2, 0, 0, 0);
    acc3 = __builtin_amdgcn_mfma_f32_16x16x32_bf16(a0, b3_0, acc3, 0, 0, 0);
    acc0 = __builtin_amdgcn_mfma_f32_16x16x32_bf16(a1, b0_1, acc0, 0, 0, 0);
    acc1 = __builtin_amdgcn_mfma_f32_16x16x32_bf16(a1, b1_1, acc1, 0, 0, 0);
    acc2 = __builtin_amdgcn_mfma_f32_16x16x32_bf16(a1, b2_1, acc2, 0, 0, 0);
    acc3 = __builtin_amdgcn_mfma_f32_16x16x32_bf16(a1, b3_1, acc3, 0, 0, 0);
    acc0 = __builtin_amdgcn_mfma_f32_16x16x32_bf16(a2, b0_2, acc0, 0, 0, 0);
    acc1 = __builtin_amdgcn_mfma_f32_16x16x32_bf16(a2, b1_2, acc1, 0, 0, 0);
    acc2 = __builtin_amdgcn_mfma_f32_16x16x32_bf16(a2, b2_2, acc2, 0, 0, 0);
    acc3 = __builtin_amdgcn_mfma_f32_16x16x32_bf16(a2, b3_2, acc3, 0, 0, 0);
    acc0 = __builtin_amdgcn_mfma_f32_16x16x32_bf16(a3, b0_3, acc0, 0, 0, 0);
    acc1 = __builtin_amdgcn_mfma_f32_16x16x32_bf16(a3, b1_3, acc1, 0, 0, 0);
    acc2 = __builtin_amdgcn_mfma_f32_16x16x32_bf16(a3, b2_3, acc2, 0, 0, 0);
    acc3 = __builtin_amdgcn_mfma_f32_16x16x32_bf16(a3, b3_3, acc3, 0, 0, 0);
    #pragma unroll
    for (int rr=0;rr<4;rr++){
      int row = m0 + lq*4 + rr;
      uint2 pk;
      pk.x = pack_bf2(acc0[rr] + bias.x, acc1[rr] + bias.y);
      pk.y = pack_bf2(acc2[rr] + bias.z, acc3[rr] + bias.w);
      *(uint2*)(void*)(Out + (size_t)row*N + n0 + 4*lr) = pk;
    }
  }
}

// ---------------------------------------------------------------------------
// Node-update helpers
// ---------------------------------------------------------------------------
static __device__ __forceinline__ float act_msg(float f, float s){
  float sig = __builtin_amdgcn_rcpf(1.f + __builtin_amdgcn_exp2f(f * -1.44269504f));
  float e   = __builtin_amdgcn_exp2f(fminf(s, 60.f) * 1.44269504f);
  float sp  = 0.69314718f * __builtin_amdgcn_logf(1.f + e);
  return sig * sp;
}

#define BN_RSQ 0.9999950000374997f   /* 1/sqrt(1+1e-5) */

static __device__ __forceinline__ void edge_nb(uint2 g, uint2 t,
                                               f32x2 fd2, f32x2 sd2, f32x2& acc){
  f32x2 f2, s2;
  f2.x = u2f_lo(g.x) + u2f_lo(t.x);
  f2.y = u2f_lo(g.y) + u2f_lo(t.y);
  s2.x = u2f_hi(g.x) + u2f_hi(t.x);
  s2.y = u2f_hi(g.y) + u2f_hi(t.y);
  f2 += fd2; s2 += sd2;
  acc.x += act_msg(f2.x, s2.x);
  acc.y += act_msg(f2.y, s2.y);
}

static __device__ __forceinline__ void ln_stats_w(float v0, float v1, float& mu, float& var){
  float s = v0 + v1, q = v0*v0 + v1*v1;
  #pragma unroll
  for (int o=32;o>=1;o>>=1){ s += __shfl_xor(s,o,64); q += __shfl_xor(q,o,64); }
  mu = s * (1.f/128.f);
  var = q * (1.f/128.f) - mu*mu;
}

// CSR aggregation: 64-edge chunk of {src,bin} in registers; per edge
// 2 readlane (SALU) + 2 gathers. Rotation-free 3-stage modulo schedule.
static __device__ __forceinline__ void aggregate(
    const int2* __restrict__ ev_arr, int e0, int e1,
    const uint2* __restrict__ G, int gstride, int goff,
    const uint2* __restrict__ Tb, int lane,
    f32x2 fd2, f32x2 sd2, f32x2& acc)
{
  for (int base = e0; base < e1; base += 64){
    int idx = base + lane;
    int2 ev = ev_arr[(idx < e1) ? idx : (e1-1)];
    float dd = __int_as_float(ev.y);
    int bnv = (int)__fmaf_rn(dd, (float)NBIN/8.0f, 0.5f);
    bnv = (bnv > NBIN) ? NBIN : bnv;
    int cnt = e1 - base; cnt = (cnt > 64) ? 64 : cnt;
    uint2 gA, tA, gB, tB, gC, tC;
    #define LDJ(gX, tX, j) { \
      int s_ = __builtin_amdgcn_readlane(ev.x, (j)); \
      int b_ = __builtin_amdgcn_readlane(bnv, (j)); \
      gX = G[(size_t)s_*gstride + goff + lane]; \
      tX = Tb[(size_t)b_*64 + lane]; }
    LDJ(gA, tA, 0);
    if (cnt > 1) LDJ(gB, tB, 1);
    if (cnt > 2) LDJ(gC, tC, 2);
    int j = 0;
    for (; j+5 < cnt; j += 3){
      edge_nb(gA, tA, fd2, sd2, acc); LDJ(gA, tA, j+3);
      edge_nb(gB, tB, fd2, sd2, acc); LDJ(gB, tB, j+4);
      edge_nb(gC, tC, fd2, sd2, acc); LDJ(gC, tC, j+5);
    }
    int rem = cnt - j;              // 1..5
    edge_nb(gA, tA, fd2, sd2, acc);
    if (rem > 3) LDJ(gA, tA, j+3);
    if (rem > 1) edge_nb(gB, tB, fd2, sd2, acc);
    if (rem > 4) LDJ(gB, tB, j+4);
    if (rem > 2) edge_nb(gC, tC, fd2, sd2, acc);
    if (rem > 3) edge_nb(gA, tA, fd2, sd2, acc);
    if (rem > 4) edge_nb(gB, tB, fd2, sd2, acc);
    #undef LDJ
  }
}

// ---------------------------------------------------------------------------
// Node update v2: 2 waves per node (split edge lists), LDS combine.
// Block = 4 waves = 2 nodes. Blocks [0,PB2) protein, rest ligand.
// lds layout (float2 units): idx = ((nib*2 + rel)*2 + pw)*64 + lane
// ---------------------------------------------------------------------------
__global__ void __launch_bounds__(256) node_update(
    const bf16* __restrict__ PT, const bf16* __restrict__ LT,
    const float* __restrict__ xp, const float* __restrict__ xl,
    const int* __restrict__ pp_rp, const int2* __restrict__ pp_e2,
    const int* __restrict__ lp_rp, const int2* __restrict__ lp_e2,
    const int* __restrict__ pl_rp, const int2* __restrict__ pl_e2,
    const bf16* __restrict__ T2,
    const float* __restrict__ bn_w, const float* __restrict__ bn_b,
    const float* __restrict__ ln_w, const float* __restrict__ ln_b,
    float* __restrict__ xp_out, bf16* __restrict__ xp_bf,
    float* __restrict__ xl_out, bf16* __restrict__ xl_bf,
    int layer, int NP, int NL, int PB2)
{
  __shared__ float2 lds[512];   // 4 KB: [nib][rel][pw][64 lanes]
  int wave = threadIdx.x >> 6;
  int lane = threadIdx.x & 63;
  int nib = wave >> 1, pw = wave & 1;
  const uint2* PTg = (const uint2*)(const void*)PT;
  bool isP = (int)blockIdx.x < PB2;
  int node = isP ? ((int)blockIdx.x*2 + nib) : (((int)blockIdx.x - PB2)*2 + nib);
  bool active = isP ? (node < NP) : (node < NL);
  f32x2 accA = {0.f,0.f};   // pp (protein) or pl (ligand) partial
  f32x2 accB = {0.f,0.f};   // lp (protein) partial
  float2 x = make_float2(0.f, 0.f);
  if (active){
    if (isP){
      x = ((const float2*)(const void*)(xp + (size_t)node*H))[lane];
      const uint32* PTu = (const uint32*)(const void*)PT;
      const uint2*  LTg = (const uint2*)(const void*)LT;
      { // pp half
        int pr = layer*3 + 0;
        uint32 fdp = PTu[(size_t)node*512 + 256 + lane];
        uint32 sdp = PTu[(size_t)node*512 + 320 + lane];
        const uint2* Tb = (const uint2*)(const void*)(T2 + (size_t)pr*(NBIN+1)*256);
        f32x2 fd2 = {u2f_lo(fdp), u2f_hi(fdp)};
        f32x2 sd2 = {u2f_lo(sdp), u2f_hi(sdp)};
        int e0 = pp_rp[node], e1 = pp_rp[node+1];
        int h = (e1 - e0 + 1) >> 1;
        int a0 = e0 + pw*h, a1 = pw ? e1 : (e0 + h);
        aggregate(pp_e2, a0, a1, PTg, 256, 0, Tb, lane, fd2, sd2, accA);
      }
      { // lp half
        int pr = layer*3 + 1;
        uint32 fdp = PTu[(size_t)node*512 + 384 + lane];
        uint32 sdp = PTu[(size_t)node*512 + 448 + lane];
        const uint2* Tb = (const uint2*)(const void*)(T2 + (size_t)pr*(NBIN+1)*256);
        f32x2 fd2 = {u2f_lo(fdp), u2f_hi(fdp)};
        f32x2 sd2 = {u2f_lo(sdp), u2f_hi(sdp)};
        int e0 = lp_rp[node], e1 = lp_rp[node+1];
        int h = (e1 - e0 + 1) >> 1;
        int a0 = e0 + pw*h, a1 = pw ? e1 : (e0 + h);
        aggregate(lp_e2, a0, a1, LTg, 128, 0, Tb, lane, fd2, sd2, accB);
      }
    } else {
      x = ((const float2*)(const void*)(xl + (size_t)node*H))[lane];
      const uint32* LTu = (const uint32*)(const void*)LT;
      int pr = layer*3 + 2;
      uint32 fdp = LTu[(size_t)node*256 + 128 + lane];
      uint32 sdp = LTu[(size_t)node*256 + 192 + lane];
      const uint2* Tb = (const uint2*)(const void*)(T2 + (size_t)pr*(NBIN+1)*256);
      f32x2 fd2 = {u2f_lo(fdp), u2f_hi(fdp)};
      f32x2 sd2 = {u2f_lo(sdp), u2f_hi(sdp)};
      int e0 = pl_rp[node], e1 = pl_rp[node+1];
      int h = (e1 - e0 + 1) >> 1;
      int a0 = e0 + pw*h, a1 = pw ? e1 : (e0 + h);
      aggregate(pl_e2, a0, a1, PTg, 256, 64, Tb, lane, fd2, sd2, accA);
    }
  }
  // publish partials
  lds[((nib*2 + 0)*2 + pw)*64 + lane] = make_float2(accA.x, accA.y);
  lds[((nib*2 + 1)*2 + pw)*64 + lane] = make_float2(accB.x, accB.y);
  __syncthreads();
  float o0 = 0.f, o1 = 0.f;
  if (active){
    if (isP){
      int rel = pw;                  // wave0 -> pp, wave1 -> lp
      float2 partner = lds[((nib*2 + rel)*2 + (1 - pw))*64 + lane];
      f32x2 acc = (pw == 0) ? accA : accB;
      acc.x += partner.x; acc.y += partner.y;
      int pr = layer*3 + rel;
      float2 bw = ((const float2*)(const void*)(bn_w + pr*H))[lane];
      float2 bb = ((const float2*)(const void*)(bn_b + pr*H))[lane];
      float2 lw = ((const float2*)(const void*)(ln_w + pr*H))[lane];
      float2 lb = ((const float2*)(const void*)(ln_b + pr*H))[lane];
      float v0 = acc.x * (bw.x * BN_RSQ) + bb.x + x.x;
      float v1 = acc.y * (bw.y * BN_RSQ) + bb.y + x.y;
      float mu, var; ln_stats_w(v0, v1, mu, var);
      float rs = rsqrtf(var + 1e-5f);
      o0 = fmaxf((v0-mu)*rs*lw.x + lb.x, 0.f) + x.x;
      o1 = fmaxf((v1-mu)*rs*lw.y + lb.y, 0.f) + x.y;
      if (pw == 1) lds[((nib*2 + 1)*2 + 1)*64 + lane] = make_float2(o0, o1);
    } else if (pw == 0){
      float2 partner = lds[((nib*2 + 0)*2 + 1)*64 + lane];
      f32x2 acc = accA;
      acc.x += partner.x; acc.y += partner.y;
      int pr = layer*3 + 2;
      float2 bw = ((const float2*)(const void*)(bn_w + pr*H))[lane];
      float2 bb = ((const float2*)(const void*)(bn_b + pr*H))[lane];
      float2 lw = ((const float2*)(const void*)(ln_w + pr*H))[lane];
      float2 lb = ((const float2*)(const void*)(ln_b + pr*H))[lane];
      float v0 = acc.x * (bw.x * BN_RSQ) + bb.x + x.x;
      float v1 = acc.y * (bw.y * BN_RSQ) + bb.y + x.y;
      float mu, var; ln_stats_w(v0, v1, mu, var);
      float rs = rsqrtf(var + 1e-5f);
      float out0 = fmaxf((v0-mu)*rs*lw.x + lb.x, 0.f) + x.x;
      float out1 = fmaxf((v1-mu)*rs*lw.y + lb.y, 0.f) + x.y;
      ((float2*)(void*)(xl_out + (size_t)node*H))[lane] = make_float2(out0, out1);
      ((uint32*)(void*)(xl_bf + (size_t)node*H))[lane] = pack_bf2(out0, out1);
    }
  }
  __syncthreads();
  if (active && isP && pw == 0){
    float2 o2 = lds[((nib*2 + 1)*2 + 1)*64 + lane];
    float out0 = o0 + o2.x, out1 = o1 + o2.y;
    ((float2*)(void*)(xp_out + (size_t)node*H))[lane] = make_float2(out0, out1);
    ((uint32*)(void*)(xp_bf + (size_t)node*H))[lane] = pack_bf2(out0, out1);
  }
}

// ---------------------------------------------------------------------------
// Final: LN(xp) @ fc_w[128,21] + fc_b
// ---------------------------------------------------------------------------
__global__ void __launch_bounds__(128) final_k(const float* __restrict__ xp,
    const float* __restrict__ lnw, const float* __restrict__ lnb,
    const float* __restrict__ fcw, const float* __restrict__ fcb,
    float* __restrict__ out, int N){
  __shared__ float sm[4];
  __shared__ float lnv[128];
  int node = blockIdx.x, c = threadIdx.x;
  float v = xp[(size_t)node*H + c];
  float s = v, q = v*v;
  #pragma unroll
  for (int o=32;o>=1;o>>=1){ s += __shfl_xor(s,o,64); q += __shfl_xor(q,o,64); }
  __syncthreads();
  if ((c & 63) == 0){ sm[(c>>6)*2] = s; sm[(c>>6)*2+1] = q; }
  __syncthreads();
  float S = sm[0] + sm[2], Q = sm[1] + sm[3];
  float mu = S * (1.f/128.f);
  float var = Q * (1.f/128.f) - mu*mu;
  float ln = (v-mu)*rsqrtf(var+1e-5f)*lnw[c] + lnb[c];
  lnv[c] = ln;
  __syncthreads();
  if (c < 21){
    float a = fcb[c];
    #pragma unroll 4
    for (int i=0;i<128;i++) a += lnv[i]*fcw[i*21+c];
    out[(size_t)node*21 + c] = a;
  }
}

// ---------------------------------------------------------------------------
extern "C" void kernel_launch(void* const* d_in, const int* in_sizes, int n_in,
                              void* d_out, int out_size, void* d_ws, size_t ws_size,
                              hipStream_t stream){
  const float* x_protein = (const float*)d_in[0];
  const float* x_ligand  = (const float*)d_in[1];
  const int*   ei_pp = (const int*)d_in[2];
  const float* ea_pp = (const float*)d_in[3];
  const int*   ei_lp = (const int*)d_in[4];
  const float* ea_lp = (const float*)d_in[5];
  const int*   ei_pl = (const int*)d_in[6];
  const float* ea_pl = (const float*)d_in[7];
  const float* Wp  = (const float*)d_in[8];
  const float* bp  = (const float*)d_in[9];
  const float* Wl  = (const float*)d_in[10];
  const float* bl  = (const float*)d_in[11];
  const float* Wf  = (const float*)d_in[12];
  const float* bfv = (const float*)d_in[13];
  const float* Wsv = (const float*)d_in[14];
  const float* bsv = (const float*)d_in[15];
  const float* bn_w = (const float*)d_in[16];
  const float* bn_b = (const float*)d_in[17];
  const float* ln_w = (const float*)d_in[18];
  const float* ln_b = (const float*)d_in[19];
  const float* lno_w = (const float*)d_in[20];
  const float* lno_b = (const float*)d_in[21];
  const float* fc_w = (const float*)d_in[22];
  const float* fc_b = (const float*)d_in[23];

  int NP  = in_sizes[0]/6, NL = in_sizes[1]/6;
  int EPP = in_sizes[3], ELP = in_sizes[5], EPL = in_sizes[7];

  char* ws = (char*)d_ws;
  size_t off = 0;
  auto alloc = [&](size_t bytes)->void*{
    void* p = ws + off; off = (off + bytes + 255) & ~(size_t)255; return p;
  };

  float* xpA = (float*)alloc((size_t)NP*H*4);
  float* xpB = (float*)alloc((size_t)NP*H*4);
  float* xlA = (float*)alloc((size_t)NL*H*4);
  float* xlB = (float*)alloc((size_t)NL*H*4);
  bf16* xp_bf = (bf16*)alloc((size_t)NP*H*2);
  bf16* xl_bf = (bf16*)alloc((size_t)NL*H*2);
  bf16* PT    = (bf16*)alloc((size_t)NP*1024*2);
  bf16* LT    = (bf16*)alloc((size_t)NL*512*2);
  bf16* Wt_p  = (bf16*)alloc((size_t)4*1024*H*2);
  bf16* Wt_l  = (bf16*)alloc((size_t)4*512*H*2);
  float* Bias_p = (float*)alloc((size_t)4*1024*4);
  float* Bias_l = (float*)alloc((size_t)4*512*4);
  bf16* T2    = (bf16*)alloc((size_t)12*(NBIN+1)*256*2);
  int* counts = (int*)alloc((size_t)(2*NP+NL)*4);
  int* rp_pp  = (int*)alloc((size_t)(NP+1)*4);
  int* cur_pp = (int*)alloc((size_t)NP*4);
  int* rp_lp  = (int*)alloc((size_t)(NP+1)*4);
  int* cur_lp = (int*)alloc((size_t)NP*4);
  int* rp_pl  = (int*)alloc((size_t)(NL+1)*4);
  int* cur_pl = (int*)alloc((size_t)NL*4);
  int2* e2_pp = (int2*)alloc((size_t)EPP*8);
  int2* e2_lp = (int2*)alloc((size_t)ELP*8);
  int2* e2_pl = (int2*)alloc((size_t)EPL*8);
  int Cpp = (NP + SCH - 1) / SCH;
  int Cpl = (NL + SCH - 1) / SCH;
  int* chsum = (int*)alloc((size_t)(2*Cpp + Cpl)*4);
  (void)ws_size; (void)n_in; (void)out_size;

  // --- prep (weights + RBF table + embeddings, one launch) ---
  size_t prep_total = (size_t)PREP_WP_N + PREP_WL_N + RBF_N + (size_t)(NP+NL)*H;
  prep_all<<<(prep_total+255)/256, 256, 0, stream>>>(Wf, Wsv, bfv, bsv,
      Wt_p, Bias_p, Wt_l, Bias_l, T2,
      x_protein, Wp, bp, xpA, xp_bf, NP,
      x_ligand,  Wl, bl, xlA, xl_bf, NL);
  // --- CSR build ---
  hipMemsetAsync(counts, 0, (size_t)(2*NP+NL)*4, stream);
  int* cnt_pp = counts; int* cnt_lp = counts + NP; int* cnt_pl = counts + 2*NP;
  int Etot = EPP + ELP + EPL;
  hist3_k<<<(Etot+255)/256, 256, 0, stream>>>(ei_pp+EPP, EPP, ei_lp+ELP, ELP, ei_pl+EPL, EPL,
                                              cnt_pp, cnt_lp, cnt_pl);
  chunksum_k<<<2*Cpp + Cpl, 256, 0, stream>>>(counts, NP, NL, Cpp, Cpl, chsum);
  scanmid_k<<<1, 192, 0, stream>>>(chsum, Cpp, Cpl, NP, NL, rp_pp, rp_lp, rp_pl);
  scanfin_k<<<2*Cpp + Cpl, 1024, 0, stream>>>(counts, NP, NL, Cpp, Cpl, chsum,
                                              rp_pp, cur_pp, rp_lp, cur_lp, rp_pl, cur_pl);
  fill3_k<<<(Etot+255)/256, 256, 0, stream>>>(ei_pp, ea_pp, EPP, ei_lp, ea_lp, ELP,
                                              ei_pl, ea_pl, EPL,
                                              cur_pp, e2_pp, cur_lp, e2_lp, cur_pl, e2_pl);

  // --- layers ---
  float* xp_cur = xpA; float* xp_nxt = xpB;
  float* xl_cur = xlA; float* xl_nxt = xlB;
  int strips_p = NP >> 4, strips_l = NL >> 4;
  int tasks_p = 16 * ((strips_p + GR - 1) / GR);
  int tasks_l = 8  * ((strips_l + GR - 1) / GR);
  int tasks_total = tasks_p + tasks_l;
  int PB2 = (NP + 1) / 2, LB2 = (NL + 1) / 2;
  for (int l=0; l<4; l++){
    gemm_tables<<<(tasks_total+3)/4, 256, 0, stream>>>(
        xp_bf, Wt_p + (size_t)l*1024*H, Bias_p + l*1024, PT, strips_p, tasks_p,
        xl_bf, Wt_l + (size_t)l*512*H,  Bias_l + l*512,  LT, strips_l, tasks_total);
    node_update<<<PB2 + LB2, 256, 0, stream>>>(PT, LT, xp_cur, xl_cur,
        rp_pp, e2_pp, rp_lp, e2_lp, rp_pl, e2_pl, T2,
        bn_w, bn_b, ln_w, ln_b, xp_nxt, xp_bf, xl_nxt, xl_bf, l, NP, NL, PB2);
    float* t;
    t = xp_cur; xp_cur = xp_nxt; xp_nxt = t;
    t = xl_cur; xl_cur = xl_nxt; xl_nxt = t;
  }

  // --- output head ---
  final_k<<<NP, 128, 0, stream>>>(xp_cur, lno_w, lno_b, fc_w, fc_b, (float*)d_out, NP);
}

// Round 12
// 807.958 us; speedup vs baseline: 1.0770x; 1.0770x over previous
//
#include <hip/hip_runtime.h>
#include <hip/hip_bf16.h>
#include <math.h>

#define H 128
#define LOG2E 1.44269504f

typedef __bf16 bf16x8 __attribute__((ext_vector_type(8)));
typedef float f32x4 __attribute__((ext_vector_type(4)));
typedef float f32x2 __attribute__((ext_vector_type(2)));
typedef __hip_bfloat16 bf16;
typedef unsigned int uint32;

static __device__ __forceinline__ float bf2f(bf16 v){ return __bfloat162float(v); }
static __device__ __forceinline__ bf16 f2bf(float v){ return __float2bfloat16(v); }
static __device__ __forceinline__ float u2f_lo(uint32 v){ return __uint_as_float(v << 16); }
static __device__ __forceinline__ float u2f_hi(uint32 v){ return __uint_as_float(v & 0xffff0000u); }

union bfpack { struct { bf16 lo, hi; } h; uint32 u; };
static __device__ __forceinline__ uint32 pack_bf2(float a, float b){
  bfpack p; p.h.lo = f2bf(a); p.h.hi = f2bf(b); return p.u;
}

// ---------------------------------------------------------------------------
// Table layouts: PT[node][1024], LT[node][512], weights permuted within
// 64-col groups. RBF nearest-bin table 256 bins (1.6 MB, L2-permanent).
// ALL f/s ingredients (weights, biases, RBF table) pre-scaled by LOG2E so the
// edge activation uses exp2/log2 without per-edge scale muls.
// CSR edge info packed as int2 {src, float_bits(d)}.
// ---------------------------------------------------------------------------
static __device__ __forceinline__ int unperm64(int r){
  int base = r & ~63; int g = r & 63; int t = g >> 4; int j = g & 15;
  return base + 4*j + t;
}

#define NBIN 256
#define PREP_WP_N (4*1024*128)
#define PREP_WL_N (4*512*128)
#define RBF_N     (12*(NBIN+1)*128)

__global__ void prep_all(const float* __restrict__ Wf, const float* __restrict__ Ws,
                         const float* __restrict__ bfv, const float* __restrict__ bsv,
                         bf16* __restrict__ Wt_p, float* __restrict__ Bias_p,
                         bf16* __restrict__ Wt_l, float* __restrict__ Bias_l,
                         bf16* __restrict__ T2,
                         const float* __restrict__ Xp, const float* __restrict__ Wp,
                         const float* __restrict__ bp, float* __restrict__ Xpo,
                         bf16* __restrict__ Xpb, int NP,
                         const float* __restrict__ Xl, const float* __restrict__ Wl,
                         const float* __restrict__ bl, float* __restrict__ Xlo,
                         bf16* __restrict__ Xlb, int NL){
  int t = blockIdx.x*blockDim.x + threadIdx.x;
  if (t < PREP_WP_N){
    int k = t & 127; int idx = t >> 7;
    int rs = idx & 1023; int l = idx >> 10;
    int r = unperm64(rs);
    int rel, c, row0; const float* W; float bias = 0.f;
    if (r < 256)      { rel=0; c=r>>1;        row0=128; W = (r&1)?Ws:Wf; }
    else if (r < 512) { rel=2; c=(r-256)>>1;  row0=128; W = (r&1)?Ws:Wf; }
    else if (r < 640) { rel=0; c=r-512; row0=0; W=Wf; bias = bfv[(l*3+rel)*H+c]; }
    else if (r < 768) { rel=0; c=r-640; row0=0; W=Ws; bias = bsv[(l*3+rel)*H+c]; }
    else if (r < 896) { rel=1; c=r-768; row0=0; W=Wf; bias = bfv[(l*3+rel)*H+c]; }
    else              { rel=1; c=r-896; row0=0; W=Ws; bias = bsv[(l*3+rel)*H+c]; }
    Wt_p[t] = f2bf(LOG2E * W[((size_t)(l*3+rel)*272 + row0 + k)*H + c]);
    if (k == 0) Bias_p[l*1024 + r] = LOG2E * bias;
    return;
  }
  t -= PREP_WP_N;
  if (t < PREP_WL_N){
    int k = t & 127; int idx = t >> 7;
    int rs = idx & 511; int l = idx >> 9;
    int r = unperm64(rs);
    int rel, c, row0; const float* W; float bias = 0.f;
    if (r < 256)      { rel=1; c=r>>1;   row0=128; W = (r&1)?Ws:Wf; }
    else if (r < 384) { rel=2; c=r-256; row0=0; W=Wf; bias = bfv[(l*3+rel)*H+c]; }
    else              { rel=2; c=r-384; row0=0; W=Ws; bias = bsv[(l*3+rel)*H+c]; }
    Wt_l[t] = f2bf(LOG2E * W[((size_t)(l*3+rel)*272 + row0 + k)*H + c]);
    if (k == 0) Bias_l[l*512 + r] = LOG2E * bias;
    return;
  }
  t -= PREP_WL_N;
  if (t < RBF_N){
    int c = t & 127;
    int b = (t >> 7) % (NBIN+1);
    int pr = t / ((NBIN+1)*128);
    float d0 = (float)b * (8.0f/(float)NBIN);
    const float* wf = Wf + ((size_t)pr*272 + 256)*H + c;
    const float* ws = Ws + ((size_t)pr*272 + 256)*H + c;
    float f0=0.f, s0=0.f;
    #pragma unroll
    for (int k=0;k<16;k++){
      float o = 0.533333333f*(float)k;
      float tt = d0 - o;
      float r0 = __expf(-1.7578125f*tt*tt);
      f0 += r0*wf[(size_t)k*H]; s0 += r0*ws[(size_t)k*H];
    }
    bf16* o = T2 + ((size_t)(pr*(NBIN+1) + b))*256 + 2*c;
    o[0]=f2bf(LOG2E * f0); o[1]=f2bf(LOG2E * s0);
    return;
  }
  t -= RBF_N;
  { // embeddings (unscaled — the scaled W covers the product)
    int idx = t;
    const float* Xin; const float* W; const float* b; float* Xout; bf16* Xbf;
    if (idx < NP*H){ Xin=Xp; W=Wp; b=bp; Xout=Xpo; Xbf=Xpb; }
    else { idx -= NP*H; if (idx >= NL*H) return; Xin=Xl; W=Wl; b=bl; Xout=Xlo; Xbf=Xlb; }
    int n = idx >> 7, c = idx & 127;
    float acc = b[c];
    #pragma unroll
    for (int k=0;k<6;k++) acc += Xin[n*6+k] * W[k*H+c];
    Xout[idx] = acc;
    Xbf[idx] = f2bf(acc);
  }
}

// ---------------------------------------------------------------------------
// CSR build: hist -> chunk sums -> mid scan -> final scan -> fill
// ---------------------------------------------------------------------------
__global__ void hist3_k(const int* __restrict__ dpp, int Epp,
                        const int* __restrict__ dlp, int Elp,
                        const int* __restrict__ dpl, int Epl,
                        int* __restrict__ cpp, int* __restrict__ clp, int* __restrict__ cpl){
  int e = blockIdx.x*blockDim.x + threadIdx.x;
  if (e < Epp) atomicAdd(&cpp[dpp[e]], 1);
  else if (e < Epp+Elp) atomicAdd(&clp[dlp[e-Epp]], 1);
  else if (e < Epp+Elp+Epl) atomicAdd(&cpl[dpl[e-Epp-Elp]], 1);
}

#define SCH 1024   // scan chunk size

__global__ void __launch_bounds__(256) chunksum_k(
    const int* __restrict__ counts, int NP, int NL, int Cpp, int Cpl,
    int* __restrict__ chsum){
  __shared__ int wred[4];
  int b = blockIdx.x;
  const int* cnt; int n; int ch;
  if (b < Cpp){ cnt = counts; n = NP; ch = b; }
  else if (b < 2*Cpp){ cnt = counts + NP; n = NP; ch = b - Cpp; }
  else { cnt = counts + 2*NP; n = NL; ch = b - 2*Cpp; }
  int base = ch * SCH;
  int tid = threadIdx.x;
  int s = 0;
  #pragma unroll
  for (int j=0;j<SCH/256;j++){
    int i = base + tid + j*256;
    if (i < n) s += cnt[i];
  }
  #pragma unroll
  for (int o=32;o>=1;o>>=1) s += __shfl_xor(s,o,64);
  if ((tid & 63) == 0) wred[tid>>6] = s;
  __syncthreads();
  if (tid == 0) chsum[b] = wred[0]+wred[1]+wred[2]+wred[3];
}

__global__ void __launch_bounds__(192) scanmid_k(
    int* __restrict__ chsum, int Cpp, int Cpl, int NP, int NL,
    int* __restrict__ rp_pp, int* __restrict__ rp_lp, int* __restrict__ rp_pl){
  int wid = threadIdx.x >> 6, lane = threadIdx.x & 63;
  int C, off; int* rp_end; int n;
  if (wid == 0){ C = Cpp; off = 0;      rp_end = rp_pp; n = NP; }
  else if (wid == 1){ C = Cpp; off = Cpp; rp_end = rp_lp; n = NP; }
  else { C = Cpl; off = 2*Cpp; rp_end = rp_pl; n = NL; }
  int v = (lane < C) ? chsum[off + lane] : 0;
  int x = v;
  #pragma unroll
  for (int o=1;o<64;o<<=1){
    int y = __shfl_up(x, o, 64);
    if (lane >= o) x += y;
  }
  if (lane < C) chsum[off + lane] = x - v;
  if (lane == 63) rp_end[n] = x;
}

__global__ void __launch_bounds__(1024) scanfin_k(
    const int* __restrict__ counts, int NP, int NL, int Cpp, int Cpl,
    const int* __restrict__ chsum,
    int* __restrict__ rp_pp, int* __restrict__ cur_pp,
    int* __restrict__ rp_lp, int* __restrict__ cur_lp,
    int* __restrict__ rp_pl, int* __restrict__ cur_pl){
  __shared__ int wsum[16];
  int b = blockIdx.x;
  const int* cnt; int n, ch; int* rp; int* cur;
  if (b < Cpp){ cnt = counts; n = NP; ch = b; rp = rp_pp; cur = cur_pp; }
  else if (b < 2*Cpp){ cnt = counts + NP; n = NP; ch = b - Cpp; rp = rp_lp; cur = cur_lp; }
  else { cnt = counts + 2*NP; n = NL; ch = b - 2*Cpp; rp = rp_pl; cur = cur_pl; }
  int tid = threadIdx.x, lane = tid & 63, wid = tid >> 6;
  int i = ch*SCH + tid;
  int v = (i < n) ? cnt[i] : 0;
  int x = v;
  #pragma unroll
  for (int o=1;o<64;o<<=1){
    int y = __shfl_up(x, o, 64);
    if (lane >= o) x += y;
  }
  if (lane == 63) wsum[wid] = x;
  __syncthreads();
  if (wid == 0 && lane < 16){
    int w = wsum[lane];
    #pragma unroll
    for (int o=1;o<16;o<<=1){
      int y = __shfl_up(w, o, 64);
      if (lane >= o) w += y;
    }
    wsum[lane] = w;
  }
  __syncthreads();
  int waveoff = (wid == 0) ? 0 : wsum[wid-1];
  int ex = chsum[b] + waveoff + x - v;
  if (i < n){ rp[i] = ex; cur[i] = ex; }
}

// fill packed int2 {src, d_bits}
__global__ void fill3_k(const int* __restrict__ ei_pp, const float* __restrict__ ea_pp, int Epp,
                        const int* __restrict__ ei_lp, const float* __restrict__ ea_lp, int Elp,
                        const int* __restrict__ ei_pl, const float* __restrict__ ea_pl, int Epl,
                        int* __restrict__ cur_pp, int2* __restrict__ e2_pp,
                        int* __restrict__ cur_lp, int2* __restrict__ e2_lp,
                        int* __restrict__ cur_pl, int2* __restrict__ e2_pl){
  int e = blockIdx.x*blockDim.x + threadIdx.x;
  if (e < Epp){
    int p = atomicAdd(&cur_pp[ei_pp[Epp + e]], 1);
    e2_pp[p] = make_int2(ei_pp[e], __float_as_int(ea_pp[e]));
  } else if (e < Epp+Elp){
    int i = e - Epp;
    int p = atomicAdd(&cur_lp[ei_lp[Elp + i]], 1);
    e2_lp[p] = make_int2(ei_lp[i], __float_as_int(ea_lp[i]));
  } else if (e < Epp+Elp+Epl){
    int i = e - Epp - Elp;
    int p = atomicAdd(&cur_pl[ei_pl[Epl + i]], 1);
    e2_pl[p] = make_int2(ei_pl[i], __float_as_int(ea_pl[i]));
  }
}

// ---------------------------------------------------------------------------
// Table GEMM v4 (B-resident): wave owns one 64-col group, iterates row strips.
// ---------------------------------------------------------------------------
#define GR 8
__global__ void __launch_bounds__(256) gemm_tables(
    const bf16* __restrict__ Xp, const bf16* __restrict__ Wtp,
    const float* __restrict__ Biasp, bf16* __restrict__ Outp,
    int strips_p, int tasks_p,
    const bf16* __restrict__ Xl, const bf16* __restrict__ Wtl,
    const float* __restrict__ Biasl, bf16* __restrict__ Outl,
    int strips_l, int tasks_total){
  int wt = blockIdx.x*4 + (threadIdx.x >> 6);
  if (wt >= tasks_total) return;
  const bf16 *X, *Wt; const float* Bias; bf16* Out; int N, strips, g, chunk;
  if (wt < tasks_p){
    X=Xp; Wt=Wtp; Bias=Biasp; Out=Outp; N=1024; strips=strips_p;
    g = wt & 15; chunk = wt >> 4;
  } else {
    int w = wt - tasks_p;
    X=Xl; Wt=Wtl; Bias=Biasl; Out=Outl; N=512; strips=strips_l;
    g = w & 7; chunk = w >> 3;
  }
  int n0 = g << 6;
  int lane = threadIdx.x & 63;
  int lr = lane & 15, lq = lane >> 4;
  const bf16x8* B0 = (const bf16x8*)(const void*)(Wt + (size_t)(n0      + lr)*H);
  const bf16x8* B1 = (const bf16x8*)(const void*)(Wt + (size_t)(n0 + 16 + lr)*H);
  const bf16x8* B2 = (const bf16x8*)(const void*)(Wt + (size_t)(n0 + 32 + lr)*H);
  const bf16x8* B3 = (const bf16x8*)(const void*)(Wt + (size_t)(n0 + 48 + lr)*H);
  bf16x8 b0_0=B0[lq], b0_1=B0[4+lq], b0_2=B0[8+lq], b0_3=B0[12+lq];
  bf16x8 b1_0=B1[lq], b1_1=B1[4+lq], b1_2=B1[8+lq], b1_3=B1[12+lq];
  bf16x8 b2_0=B2[lq], b2_1=B2[4+lq], b2_2=B2[8+lq], b2_3=B2[12+lq];
  bf16x8 b3_0=B3[lq], b3_1=B3[4+lq], b3_2=B3[8+lq], b3_3=B3[12+lq];
  float4 bias = ((const float4*)(const void*)(Bias + n0))[lr];
  #pragma unroll 2
  for (int r=0;r<GR;r++){
    int strip = chunk*GR + r;
    if (strip >= strips) break;
    int m0 = strip << 4;
    const bf16x8* A = (const bf16x8*)(const void*)(X + (size_t)(m0+lr)*H);
    bf16x8 a0 = A[lq], a1 = A[4+lq], a2 = A[8+lq], a3 = A[12+lq];
    f32x4 acc0 = {0.f,0.f,0.f,0.f}, acc1 = acc0, acc2 = acc0, acc3 = acc0;
    acc0 = __builtin_amdgcn_mfma_f32_16x16x32_bf16(a0, b0_0, acc0, 0, 0, 0);
    acc1 = __builtin_amdgcn_mfma_f32_16x16x32_bf16(a0, b1_0, acc1, 0, 0, 0);
    acc2 = __builtin_amdgcn_mfma_f32_16x16x32_bf16(a0, b2_0, acc2, 0, 0, 0);
    acc3 = __builtin_amdgcn_mfma_f32_16x16x32_bf16(a0, b3_0, acc3, 0, 0, 0);
    acc0 = __builtin_amdgcn_mfma_f32_16x16x32_bf16(a1, b0_1, acc0, 0, 0, 0);
    acc1 = __builtin_amdgcn_mfma_f32_16x16x32_bf16(a1, b1_1, acc1, 0, 0, 0);
    acc2 = __builtin_amdgcn_mfma_f32_16x16x32_bf16(a1, b2_1, acc2, 0, 0, 0);
    acc3 = __builtin_amdgcn_mfma_f32_16x16x32_bf16(a1, b3_1, acc3, 0, 0, 0);
    acc0 = __builtin_amdgcn_mfma_f32_16x16x32_bf16(a2, b0_2, acc0, 0, 0, 0);
    acc1 = __builtin_amdgcn_mfma_f32_16x16x32_bf16(a2, b1_2, acc1, 0, 0, 0);
    acc2 = __builtin_amdgcn_mfma_f32_16x16x32_bf16(a2, b2_2, acc2, 0, 0, 0);
    acc3 = __builtin_amdgcn_mfma_f32_16x16x32_bf16(a2, b3_2, acc3, 0, 0, 0);
    acc0 = __builtin_amdgcn_mfma_f32_16x16x32_bf16(a3, b0_3, acc0, 0, 0, 0);
    acc1 = __builtin_amdgcn_mfma_f32_16x16x32_bf16(a3, b1_3, acc1, 0, 0, 0);
    acc2 = __builtin_amdgcn_mfma_f32_16x16x32_bf16(a3, b2_3, acc2, 0, 0, 0);
    acc3 = __builtin_amdgcn_mfma_f32_16x16x32_bf16(a3, b3_3, acc3, 0, 0, 0);
    #pragma unroll
    for (int rr=0;rr<4;rr++){
      int row = m0 + lq*4 + rr;
      uint2 pk;
      pk.x = pack_bf2(acc0[rr] + bias.x, acc1[rr] + bias.y);
      pk.y = pack_bf2(acc2[rr] + bias.z, acc3[rr] + bias.w);
      *(uint2*)(void*)(Out + (size_t)row*N + n0 + 4*lr) = pk;
    }
  }
}

// ---------------------------------------------------------------------------
// Node-update helpers (inputs pre-scaled by LOG2E)
// ---------------------------------------------------------------------------
static __device__ __forceinline__ float act_msg(float F, float S){
  float sig = __builtin_amdgcn_rcpf(1.f + __builtin_amdgcn_exp2f(-F));
  float e   = __builtin_amdgcn_exp2f(fminf(S, 86.f));
  float sp  = 0.69314718f * __builtin_amdgcn_logf(1.f + e);
  return sig * sp;
}

#define BN_RSQ 0.9999950000374997f   /* 1/sqrt(1+1e-5) */

static __device__ __forceinline__ void edge_nb(uint2 g, uint2 t,
                                               f32x2 fd2, f32x2 sd2, f32x2& acc){
  f32x2 f2, s2;
  f2.x = u2f_lo(g.x) + u2f_lo(t.x);
  f2.y = u2f_lo(g.y) + u2f_lo(t.y);
  s2.x = u2f_hi(g.x) + u2f_hi(t.x);
  s2.y = u2f_hi(g.y) + u2f_hi(t.y);
  f2 += fd2; s2 += sd2;
  acc.x += act_msg(f2.x, s2.x);
  acc.y += act_msg(f2.y, s2.y);
}

static __device__ __forceinline__ void ln_stats_w(float v0, float v1, float& mu, float& var){
  float s = v0 + v1, q = v0*v0 + v1*v1;
  #pragma unroll
  for (int o=32;o>=1;o>>=1){ s += __shfl_xor(s,o,64); q += __shfl_xor(q,o,64); }
  mu = s * (1.f/128.f);
  var = q * (1.f/128.f) - mu*mu;
}

// CSR aggregation: 64-edge chunk of {src,bin} in registers; per edge
// 2 readlane (SALU) + 2 gathers. Rotation-free 3-stage modulo schedule.
static __device__ __forceinline__ void aggregate(
    const int2* __restrict__ ev_arr, int e0, int e1,
    const uint2* __restrict__ G, int gstride, int goff,
    const uint2* __restrict__ Tb, int lane,
    f32x2 fd2, f32x2 sd2, f32x2& acc)
{
  for (int base = e0; base < e1; base += 64){
    int idx = base + lane;
    int2 ev = ev_arr[(idx < e1) ? idx : (e1-1)];
    float dd = __int_as_float(ev.y);
    int bnv = (int)__fmaf_rn(dd, (float)NBIN/8.0f, 0.5f);
    bnv = (bnv > NBIN) ? NBIN : bnv;
    int cnt = e1 - base; cnt = (cnt > 64) ? 64 : cnt;
    uint2 gA, tA, gB, tB, gC, tC;
    #define LDJ(gX, tX, j) { \
      int s_ = __builtin_amdgcn_readlane(ev.x, (j)); \
      int b_ = __builtin_amdgcn_readlane(bnv, (j)); \
      gX = G[(size_t)s_*gstride + goff + lane]; \
      tX = Tb[(size_t)b_*64 + lane]; }
    LDJ(gA, tA, 0);
    if (cnt > 1) LDJ(gB, tB, 1);
    if (cnt > 2) LDJ(gC, tC, 2);
    int j = 0;
    for (; j+5 < cnt; j += 3){
      edge_nb(gA, tA, fd2, sd2, acc); LDJ(gA, tA, j+3);
      edge_nb(gB, tB, fd2, sd2, acc); LDJ(gB, tB, j+4);
      edge_nb(gC, tC, fd2, sd2, acc); LDJ(gC, tC, j+5);
    }
    int rem = cnt - j;              // 1..5
    edge_nb(gA, tA, fd2, sd2, acc);
    if (rem > 3) LDJ(gA, tA, j+3);
    if (rem > 1) edge_nb(gB, tB, fd2, sd2, acc);
    if (rem > 4) LDJ(gB, tB, j+4);
    if (rem > 2) edge_nb(gC, tC, fd2, sd2, acc);
    if (rem > 3) edge_nb(gA, tA, fd2, sd2, acc);
    if (rem > 4) edge_nb(gB, tB, fd2, sd2, acc);
    #undef LDJ
  }
}

// ---------------------------------------------------------------------------
// Merged node update (R10 form): wave per node. Blocks [0,PB) protein, rest ligand.
// ---------------------------------------------------------------------------
__global__ void __launch_bounds__(256) node_update(
    const bf16* __restrict__ PT, const bf16* __restrict__ LT,
    const float* __restrict__ xp, const float* __restrict__ xl,
    const int* __restrict__ pp_rp, const int2* __restrict__ pp_e2,
    const int* __restrict__ lp_rp, const int2* __restrict__ lp_e2,
    const int* __restrict__ pl_rp, const int2* __restrict__ pl_e2,
    const bf16* __restrict__ T2,
    const float* __restrict__ bn_w, const float* __restrict__ bn_b,
    const float* __restrict__ ln_w, const float* __restrict__ ln_b,
    float* __restrict__ xp_out, bf16* __restrict__ xp_bf,
    float* __restrict__ xl_out, bf16* __restrict__ xl_bf,
    int layer, int NP, int NL, int PB)
{
  int wave = threadIdx.x >> 6;
  int lane = threadIdx.x & 63;
  const uint2* PTg = (const uint2*)(const void*)PT;
  if ((int)blockIdx.x < PB){
    int node = blockIdx.x*4 + wave;
    if (node >= NP) return;
    float2 x = ((const float2*)(const void*)(xp + (size_t)node*H))[lane];
    const uint32* PTu = (const uint32*)(const void*)PT;
    const uint2*  LTg = (const uint2*)(const void*)LT;
    float o1_0, o1_1, o2_0, o2_1;
    { // relation pp
      int pr = layer*3 + 0;
      uint32 fdp = PTu[(size_t)node*512 + 256 + lane];
      uint32 sdp = PTu[(size_t)node*512 + 320 + lane];
      const uint2* Tb = (const uint2*)(const void*)(T2 + (size_t)pr*(NBIN+1)*256);
      f32x2 fd2 = {u2f_lo(fdp), u2f_hi(fdp)};
      f32x2 sd2 = {u2f_lo(sdp), u2f_hi(sdp)};
      f32x2 acc = {0.f, 0.f};
      aggregate(pp_e2, pp_rp[node], pp_rp[node+1], PTg, 256, 0, Tb, lane, fd2, sd2, acc);
      float2 bw = ((const float2*)(const void*)(bn_w + pr*H))[lane];
      float2 bb = ((const float2*)(const void*)(bn_b + pr*H))[lane];
      float2 lw = ((const float2*)(const void*)(ln_w + pr*H))[lane];
      float2 lb = ((const float2*)(const void*)(ln_b + pr*H))[lane];
      float v0 = acc.x * (bw.x * BN_RSQ) + bb.x + x.x;
      float v1 = acc.y * (bw.y * BN_RSQ) + bb.y + x.y;
      float mu, var; ln_stats_w(v0, v1, mu, var);
      float rs = rsqrtf(var + 1e-5f);
      o1_0 = fmaxf((v0-mu)*rs*lw.x + lb.x, 0.f) + x.x;
      o1_1 = fmaxf((v1-mu)*rs*lw.y + lb.y, 0.f) + x.y;
    }
    { // relation lp
      int pr = layer*3 + 1;
      uint32 fdp = PTu[(size_t)node*512 + 384 + lane];
      uint32 sdp = PTu[(size_t)node*512 + 448 + lane];
      const uint2* Tb = (const uint2*)(const void*)(T2 + (size_t)pr*(NBIN+1)*256);
      f32x2 fd2 = {u2f_lo(fdp), u2f_hi(fdp)};
      f32x2 sd2 = {u2f_lo(sdp), u2f_hi(sdp)};
      f32x2 acc = {0.f, 0.f};
      aggregate(lp_e2, lp_rp[node], lp_rp[node+1], LTg, 128, 0, Tb, lane, fd2, sd2, acc);
      float2 bw = ((const float2*)(const void*)(bn_w + pr*H))[lane];
      float2 bb = ((const float2*)(const void*)(bn_b + pr*H))[lane];
      float2 lw = ((const float2*)(const void*)(ln_w + pr*H))[lane];
      float2 lb = ((const float2*)(const void*)(ln_b + pr*H))[lane];
      float v0 = acc.x * (bw.x * BN_RSQ) + bb.x + x.x;
      float v1 = acc.y * (bw.y * BN_RSQ) + bb.y + x.y;
      float mu, var; ln_stats_w(v0, v1, mu, var);
      float rs = rsqrtf(var + 1e-5f);
      o2_0 = fmaxf((v0-mu)*rs*lw.x + lb.x, 0.f) + x.x;
      o2_1 = fmaxf((v1-mu)*rs*lw.y + lb.y, 0.f) + x.y;
    }
    float out0 = o1_0 + o2_0, out1 = o1_1 + o2_1;
    ((float2*)(void*)(xp_out + (size_t)node*H))[lane] = make_float2(out0, out1);
    ((uint32*)(void*)(xp_bf + (size_t)node*H))[lane] = pack_bf2(out0, out1);
  } else {
    int node = (blockIdx.x - PB)*4 + wave;
    if (node >= NL) return;
    float2 x = ((const float2*)(const void*)(xl + (size_t)node*H))[lane];
    const uint32* LTu = (const uint32*)(const void*)LT;
    int pr = layer*3 + 2;
    uint32 fdp = LTu[(size_t)node*256 + 128 + lane];
    uint32 sdp = LTu[(size_t)node*256 + 192 + lane];
    const uint2* Tb = (const uint2*)(const void*)(T2 + (size_t)pr*(NBIN+1)*256);
    f32x2 fd2 = {u2f_lo(fdp), u2f_hi(fdp)};
    f32x2 sd2 = {u2f_lo(sdp), u2f_hi(sdp)};
    f32x2 acc = {0.f, 0.f};
    aggregate(pl_e2, pl_rp[node], pl_rp[node+1], PTg, 256, 64, Tb, lane, fd2, sd2, acc);
    float2 bw = ((const float2*)(const void*)(bn_w + pr*H))[lane];
    float2 bb = ((const float2*)(const void*)(bn_b + pr*H))[lane];
    float2 lw = ((const float2*)(const void*)(ln_w + pr*H))[lane];
    float2 lb = ((const float2*)(const void*)(ln_b + pr*H))[lane];
    float v0 = acc.x * (bw.x * BN_RSQ) + bb.x + x.x;
    float v1 = acc.y * (bw.y * BN_RSQ) + bb.y + x.y;
    float mu, var; ln_stats_w(v0, v1, mu, var);
    float rs = rsqrtf(var + 1e-5f);
    float out0 = fmaxf((v0-mu)*rs*lw.x + lb.x, 0.f) + x.x;
    float out1 = fmaxf((v1-mu)*rs*lw.y + lb.y, 0.f) + x.y;
    ((float2*)(void*)(xl_out + (size_t)node*H))[lane] = make_float2(out0, out1);
    ((uint32*)(void*)(xl_bf + (size_t)node*H))[lane] = pack_bf2(out0, out1);
  }
}

// ---------------------------------------------------------------------------
// Final: LN(xp) @ fc_w[128,21] + fc_b
// ---------------------------------------------------------------------------
__global__ void __launch_bounds__(128) final_k(const float* __restrict__ xp,
    const float* __restrict__ lnw, const float* __restrict__ lnb,
    const float* __restrict__ fcw, const float* __restrict__ fcb,
    float* __restrict__ out, int N){
  __shared__ float sm[4];
  __shared__ float lnv[128];
  int node = blockIdx.x, c = threadIdx.x;
  float v = xp[(size_t)node*H + c];
  float s = v, q = v*v;
  #pragma unroll
  for (int o=32;o>=1;o>>=1){ s += __shfl_xor(s,o,64); q += __shfl_xor(q,o,64); }
  __syncthreads();
  if ((c & 63) == 0){ sm[(c>>6)*2] = s; sm[(c>>6)*2+1] = q; }
  __syncthreads();
  float S = sm[0] + sm[2], Q = sm[1] + sm[3];
  float mu = S * (1.f/128.f);
  float var = Q * (1.f/128.f) - mu*mu;
  float ln = (v-mu)*rsqrtf(var+1e-5f)*lnw[c] + lnb[c];
  lnv[c] = ln;
  __syncthreads();
  if (c < 21){
    float a = fcb[c];
    #pragma unroll 4
    for (int i=0;i<128;i++) a += lnv[i]*fcw[i*21+c];
    out[(size_t)node*21 + c] = a;
  }
}

// ---------------------------------------------------------------------------
extern "C" void kernel_launch(void* const* d_in, const int* in_sizes, int n_in,
                              void* d_out, int out_size, void* d_ws, size_t ws_size,
                              hipStream_t stream){
  const float* x_protein = (const float*)d_in[0];
  const float* x_ligand  = (const float*)d_in[1];
  const int*   ei_pp = (const int*)d_in[2];
  const float* ea_pp = (const float*)d_in[3];
  const int*   ei_lp = (const int*)d_in[4];
  const float* ea_lp = (const float*)d_in[5];
  const int*   ei_pl = (const int*)d_in[6];
  const float* ea_pl = (const float*)d_in[7];
  const float* Wp  = (const float*)d_in[8];
  const float* bp  = (const float*)d_in[9];
  const float* Wl  = (const float*)d_in[10];
  const float* bl  = (const float*)d_in[11];
  const float* Wf  = (const float*)d_in[12];
  const float* bfv = (const float*)d_in[13];
  const float* Wsv = (const float*)d_in[14];
  const float* bsv = (const float*)d_in[15];
  const float* bn_w = (const float*)d_in[16];
  const float* bn_b = (const float*)d_in[17];
  const float* ln_w = (const float*)d_in[18];
  const float* ln_b = (const float*)d_in[19];
  const float* lno_w = (const float*)d_in[20];
  const float* lno_b = (const float*)d_in[21];
  const float* fc_w = (const float*)d_in[22];
  const float* fc_b = (const float*)d_in[23];

  int NP  = in_sizes[0]/6, NL = in_sizes[1]/6;
  int EPP = in_sizes[3], ELP = in_sizes[5], EPL = in_sizes[7];

  char* ws = (char*)d_ws;
  size_t off = 0;
  auto alloc = [&](size_t bytes)->void*{
    void* p = ws + off; off = (off + bytes + 255) & ~(size_t)255; return p;
  };

  float* xpA = (float*)alloc((size_t)NP*H*4);
  float* xpB = (float*)alloc((size_t)NP*H*4);
  float* xlA = (float*)alloc((size_t)NL*H*4);
  float* xlB = (float*)alloc((size_t)NL*H*4);
  bf16* xp_bf = (bf16*)alloc((size_t)NP*H*2);
  bf16* xl_bf = (bf16*)alloc((size_t)NL*H*2);
  bf16* PT    = (bf16*)alloc((size_t)NP*1024*2);
  bf16* LT    = (bf16*)alloc((size_t)NL*512*2);
  bf16* Wt_p  = (bf16*)alloc((size_t)4*1024*H*2);
  bf16* Wt_l  = (bf16*)alloc((size_t)4*512*H*2);
  float* Bias_p = (float*)alloc((size_t)4*1024*4);
  float* Bias_l = (float*)alloc((size_t)4*512*4);
  bf16* T2    = (bf16*)alloc((size_t)12*(NBIN+1)*256*2);
  int* counts = (int*)alloc((size_t)(2*NP+NL)*4);
  int* rp_pp  = (int*)alloc((size_t)(NP+1)*4);
  int* cur_pp = (int*)alloc((size_t)NP*4);
  int* rp_lp  = (int*)alloc((size_t)(NP+1)*4);
  int* cur_lp = (int*)alloc((size_t)NP*4);
  int* rp_pl  = (int*)alloc((size_t)(NL+1)*4);
  int* cur_pl = (int*)alloc((size_t)NL*4);
  int2* e2_pp = (int2*)alloc((size_t)EPP*8);
  int2* e2_lp = (int2*)alloc((size_t)ELP*8);
  int2* e2_pl = (int2*)alloc((size_t)EPL*8);
  int Cpp = (NP + SCH - 1) / SCH;
  int Cpl = (NL + SCH - 1) / SCH;
  int* chsum = (int*)alloc((size_t)(2*Cpp + Cpl)*4);
  (void)ws_size; (void)n_in; (void)out_size;

  // --- prep (weights + RBF table + embeddings, one launch) ---
  size_t prep_total = (size_t)PREP_WP_N + PREP_WL_N + RBF_N + (size_t)(NP+NL)*H;
  prep_all<<<(prep_total+255)/256, 256, 0, stream>>>(Wf, Wsv, bfv, bsv,
      Wt_p, Bias_p, Wt_l, Bias_l, T2,
      x_protein, Wp, bp, xpA, xp_bf, NP,
      x_ligand,  Wl, bl, xlA, xl_bf, NL);
  // --- CSR build ---
  hipMemsetAsync(counts, 0, (size_t)(2*NP+NL)*4, stream);
  int* cnt_pp = counts; int* cnt_lp = counts + NP; int* cnt_pl = counts + 2*NP;
  int Etot = EPP + ELP + EPL;
  hist3_k<<<(Etot+255)/256, 256, 0, stream>>>(ei_pp+EPP, EPP, ei_lp+ELP, ELP, ei_pl+EPL, EPL,
                                              cnt_pp, cnt_lp, cnt_pl);
  chunksum_k<<<2*Cpp + Cpl, 256, 0, stream>>>(counts, NP, NL, Cpp, Cpl, chsum);
  scanmid_k<<<1, 192, 0, stream>>>(chsum, Cpp, Cpl, NP, NL, rp_pp, rp_lp, rp_pl);
  scanfin_k<<<2*Cpp + Cpl, 1024, 0, stream>>>(counts, NP, NL, Cpp, Cpl, chsum,
                                              rp_pp, cur_pp, rp_lp, cur_lp, rp_pl, cur_pl);
  fill3_k<<<(Etot+255)/256, 256, 0, stream>>>(ei_pp, ea_pp, EPP, ei_lp, ea_lp, ELP,
                                              ei_pl, ea_pl, EPL,
                                              cur_pp, e2_pp, cur_lp, e2_lp, cur_pl, e2_pl);

  // --- layers ---
  float* xp_cur = xpA; float* xp_nxt = xpB;
  float* xl_cur = xlA; float* xl_nxt = xlB;
  int strips_p = NP >> 4, strips_l = NL >> 4;
  int tasks_p = 16 * ((strips_p + GR - 1) / GR);
  int tasks_l = 8  * ((strips_l + GR - 1) / GR);
  int tasks_total = tasks_p + tasks_l;
  int PB = (NP + 3) / 4, LB = (NL + 3) / 4;
  for (int l=0; l<4; l++){
    gemm_tables<<<(tasks_total+3)/4, 256, 0, stream>>>(
        xp_bf, Wt_p + (size_t)l*1024*H, Bias_p + l*1024, PT, strips_p, tasks_p,
        xl_bf, Wt_l + (size_t)l*512*H,  Bias_l + l*512,  LT, strips_l, tasks_total);
    node_update<<<PB + LB, 256, 0, stream>>>(PT, LT, xp_cur, xl_cur,
        rp_pp, e2_pp, rp_lp, e2_lp, rp_pl, e2_pl, T2,
        bn_w, bn_b, ln_w, ln_b, xp_nxt, xp_bf, xl_nxt, xl_bf, l, NP, NL, PB);
    float* t;
    t = xp_cur; xp_cur = xp_nxt; xp_nxt = t;
    t = xl_cur; xl_cur = xl_nxt; xl_nxt = t;
  }

  // --- output head ---
  final_k<<<NP, 128, 0, stream>>>(xp_cur, lno_w, lno_b, fc_w, fc_b, (float*)d_out, NP);
}